// Round 7
// baseline (189.444 us; speedup 1.0000x reference)
//
#include <hip/hip_runtime.h>
#include <math.h>

#define BB 16
#define CC 32
#define OO 32
#define HH 256
#define WW 256
#define HW (HH * WW)
#define PD 8
#define HP (HH + 2 * PD)      // 272
#define WP (WW + 2 * PD)      // 272

typedef __attribute__((ext_vector_type(8))) short bf16x8;
typedef __attribute__((ext_vector_type(4))) float f32x4;
typedef __attribute__((ext_vector_type(4))) unsigned short us4;
typedef __attribute__((ext_vector_type(8))) unsigned short us8;

__device__ __forceinline__ unsigned short f2bf(float f) {
    unsigned u = __float_as_uint(f);
    u += 0x7fffu + ((u >> 16) & 1u);     // round-to-nearest-even
    return (unsigned short)(u >> 16);
}
__device__ __forceinline__ float bf2f(unsigned short v) {
    return __uint_as_float((unsigned)v << 16);
}

// ---------------------------------------------------------------------------
// Kernel 1: 5x5 separable Gaussian blur -> zero-padded channels-last bf16
//   xbt[b][y=h+PD][x=w+PD][c].  (unchanged from R5)
// ---------------------------------------------------------------------------
__global__ __launch_bounds__(256) void blur_t_kernel(const float* __restrict__ x,
                                                     const float* __restrict__ sigma_p,
                                                     unsigned short* __restrict__ xbt) {
    __shared__ __align__(16) unsigned short vb[16][4][264];   // [c%16][row][col+4]
    const int t   = threadIdx.x;
    const int blk = ((blockIdx.x & 7) << 7) + (blockIdx.x >> 3);   // 1024 blocks, chunk 128
    const int band = blk & 63;
    const int b    = blk >> 6;
    const int h0   = band << 2;

    const float sigma = sigma_p[0];
    const float inv2s2 = 1.0f / (2.0f * sigma * sigma);
    float e[5], s = 0.0f;
#pragma unroll
    for (int i = 0; i < 5; ++i) {
        float d = (float)(i - 2);
        e[i] = expf(-(d * d) * inv2s2);
        s += e[i];
    }
    const float inv_s = 1.0f / s;
    float wn[5];
#pragma unroll
    for (int i = 0; i < 5; ++i) wn[i] = e[i] * inv_s;

    unsigned short* xb_img = xbt + (size_t)b * (HP * WP * CC);

    // ---- halo zeroing ----
    const us8 z8 = {0, 0, 0, 0, 0, 0, 0, 0};
    {
        const int j  = t >> 6;
        const int px = (t >> 2) & 15;
        const int ch = t & 3;
        const int xx = (px < PD) ? px : px + WW;
        *reinterpret_cast<us8*>(xb_img + ((size_t)(h0 + PD + j) * WP + xx) * CC + ch * 8) = z8;
    }
    if (h0 < PD) {
#pragma unroll
        for (int j2 = 0; j2 < 4; ++j2) {
            unsigned short* dst = xb_img + (size_t)(h0 + j2) * WP * CC;
            for (int i = t; i < (WP * CC) / 8; i += 256)
                *reinterpret_cast<us8*>(dst + i * 8) = z8;
        }
    }
    if (h0 + 4 > HH - PD) {
#pragma unroll
        for (int j2 = 0; j2 < 4; ++j2) {
            unsigned short* dst = xb_img + (size_t)(h0 + j2 + 2 * PD) * WP * CC;
            for (int i = t; i < (WP * CC) / 8; i += 256)
                *reinterpret_cast<us8*>(dst + i * 8) = z8;
        }
    }

    const int g  = t & 63;
    const int cs = t >> 6;

#pragma unroll
    for (int pass = 0; pass < 2; ++pass) {
        if (pass) __syncthreads();

        {
            const int c15 = t >> 4;
            const int j   = (t >> 2) & 3;
            const int e_  = t & 3;
            const int idx = (e_ < 2) ? (2 + e_) : (258 + e_);
            vb[c15][j][idx] = 0;
        }

#pragma unroll
        for (int it = 0; it < 4; ++it) {
            const int c = (pass << 4) + (it << 2) + cs;
            const float* xc = x + ((size_t)(b * CC + c) * HH) * WW + 4 * g;
            float4 v[8];
#pragma unroll
            for (int k = 0; k < 8; ++k) {
                const int r = h0 - 2 + k;
                v[k] = (r >= 0 && r < HH) ? *reinterpret_cast<const float4*>(xc + r * WW)
                                          : make_float4(0.f, 0.f, 0.f, 0.f);
            }
#pragma unroll
            for (int j = 0; j < 4; ++j) {
                float4 a = make_float4(0.f, 0.f, 0.f, 0.f);
#pragma unroll
                for (int i = 0; i < 5; ++i) {
                    a.x = fmaf(wn[i], v[j + i].x, a.x);
                    a.y = fmaf(wn[i], v[j + i].y, a.y);
                    a.z = fmaf(wn[i], v[j + i].z, a.z);
                    a.w = fmaf(wn[i], v[j + i].w, a.w);
                }
                us4 bv;
                bv[0] = f2bf(a.x); bv[1] = f2bf(a.y);
                bv[2] = f2bf(a.z); bv[3] = f2bf(a.w);
                *reinterpret_cast<us4*>(&vb[c & 15][j][4 + 4 * g]) = bv;
            }
        }
        __syncthreads();

        const int c15 = t & 15;
        const int c   = (pass << 4) + c15;
        const int T   = t >> 4;
#pragma unroll
        for (int j = 0; j < 4; ++j) {
            us4 ch[6];
#pragma unroll
            for (int k = 0; k < 6; ++k)
                ch[k] = *reinterpret_cast<const us4*>(&vb[c15][j][16 * T + 4 * k]);
            float val[24];
#pragma unroll
            for (int q = 0; q < 24; ++q) val[q] = bf2f(ch[q >> 2][q & 3]);
            unsigned short* ob = xb_img + ((size_t)(h0 + PD + j) * WP + PD + 16 * T) * CC + c;
#pragma unroll
            for (int d = 0; d < 16; ++d) {
                float a = 0.0f;
#pragma unroll
                for (int i = 0; i < 5; ++i) a = fmaf(wn[i], val[d + 2 + i], a);
                ob[d * CC] = f2bf(a);
            }
        }
    }
}

// ---------------------------------------------------------------------------
// Kernel 2: corner table (SORTED by image offset => row-major locality) +
// pre-scaled B fragments. (unchanged from R6)
// ---------------------------------------------------------------------------
__global__ void wtrans_kernel(const float* __restrict__ wgt,
                              const float* __restrict__ sigma_p,
                              int* __restrict__ meta,
                              unsigned short* __restrict__ wb2) {
    __shared__ int   s_tap[36];
    __shared__ float s_w[36];
    __shared__ int   s_soff[36];
    __shared__ int   s_n;
    const int t = threadIdx.x;

    if (t == 0) {
        const float UY[9] = {-0.70710678f, -1.0f, -0.70710678f, 0.0f, 0.0f, 0.0f,
                              0.70710678f,  1.0f,  0.70710678f};
        const float UX[9] = {-0.70710678f, 0.0f, 0.70710678f, -1.0f, 0.0f, 1.0f,
                             -0.70710678f, 0.0f, 0.70710678f};
        const int KYI[9] = {-1, -1, -1, 0, 0, 0, 1, 1, 1};
        const int KXI[9] = {-1, 0, 1, -1, 0, 1, -1, 0, 1};
        const float s6 = sigma_p[0] * 6.0f;
        int n = 0;
        for (int s_ = 0; s_ < 9; ++s_) {
            float offy = UY[s_] * s6, offx = UX[s_] * s6;
            float fy = floorf(offy), fx = floorf(offx);
            float ty = offy - fy,    tx = offx - fx;
            int sy = KYI[s_] + (int)fy;
            int sx = KXI[s_] + (int)fx;
            float wy[2] = {1.0f - ty, ty};
            float wx[2] = {1.0f - tx, tx};
            for (int dy = 0; dy < 2; ++dy)
                for (int dx = 0; dx < 2; ++dx) {
                    float wc = wy[dy] * wx[dx];
                    if (wc != 0.0f) {
                        s_tap[n]  = s_;
                        s_w[n]    = wc;
                        s_soff[n] = ((sy + dy) * WP + (sx + dx)) * CC;
                        ++n;
                    }
                }
        }
        // insertion sort by soff (== row-major (Sy,Sx) order)
        for (int i = 1; i < n; ++i) {
            int ks = s_soff[i]; int kt = s_tap[i]; float kw = s_w[i];
            int j = i - 1;
            while (j >= 0 && s_soff[j] > ks) {
                s_soff[j + 1] = s_soff[j]; s_tap[j + 1] = s_tap[j]; s_w[j + 1] = s_w[j];
                --j;
            }
            s_soff[j + 1] = ks; s_tap[j + 1] = kt; s_w[j + 1] = kw;
        }
        if (blockIdx.x == 0) {
            meta[0] = n;
            for (int i = 0; i < n; ++i) meta[1 + i] = s_soff[i];
        }
        s_n = n;
    }
    __syncthreads();

    const int e = blockIdx.x;
    if (e >= s_n) return;
    for (int i = t; i < 1024; i += 256) {
        int j  = i & 7;
        int l  = (i >> 3) & 63;
        int nh = (i >> 9) & 1;
        int o  = nh * 16 + (l & 15);
        int c  = ((l >> 4) << 3) + j;
        wb2[e * 1024 + i] = f2bf(s_w[e] * wgt[(o * CC + c) * 9 + s_tap[e]]);
    }
}

// ---------------------------------------------------------------------------
// Kernel 3: pure-MFMA mix.
// Block = 512 threads = 8 waves = 4 consecutive rows x 2 x-segments, so all
// co-resident waves stream the SAME corner rows through the CU's L1.
// ALL B entries staged in LDS (<=72 KB) -> B never touches L1.
// Wave = 128 px = 8 M-tiles. Plain stores (NT stores caused RMW traffic, R6).
// ---------------------------------------------------------------------------
__global__ __launch_bounds__(512, 4) void mix4_kernel(const unsigned short* __restrict__ xbt,
                                                      const int* __restrict__ meta,
                                                      const unsigned short* __restrict__ wb2,
                                                      float* __restrict__ out) {
    __shared__ us8 bs8[36 * 128];            // up to 36 entries x 2 KB = 72 KB
    const int t    = threadIdx.x;
    const int lane = t & 63;
    const int wv   = t >> 6;                 // 0..7
    const int blk  = ((blockIdx.x & 7) << 7) + (blockIdx.x >> 3);  // 1024 blocks, chunk 128
    const int b    = blk >> 6;
    const int h    = ((blk & 63) << 2) + (wv >> 1);
    const int xseg = (wv & 1) << 7;          // 0 or 128
    const int mrow = lane & 15;
    const int c0   = (lane >> 4) << 3;
    const int ncorn = meta[0];

    // stage all B entries into LDS
    for (int i = t; i < ncorn * 128; i += 512)
        bs8[i] = reinterpret_cast<const us8*>(wb2)[i];
    __syncthreads();

    const unsigned short* rowp = xbt + ((size_t)(b * HP + h + PD) * WP + PD) * CC;
    const int loff = (xseg + mrow) * CC + c0;

    f32x4 acc[8][2];
#pragma unroll
    for (int tt = 0; tt < 8; ++tt) {
        acc[tt][0] = (f32x4){0.f, 0.f, 0.f, 0.f};
        acc[tt][1] = (f32x4){0.f, 0.f, 0.f, 0.f};
    }

    const unsigned short* bsp = reinterpret_cast<const unsigned short*>(bs8);
    for (int e = 0; e < ncorn; ++e) {
        const int soff = meta[1 + e];                        // wave-uniform s_load
        const bf16x8 b0 = *reinterpret_cast<const bf16x8*>(bsp + (e * 128 + lane) * 8);
        const bf16x8 b1 = *reinterpret_cast<const bf16x8*>(bsp + (e * 128 + 64 + lane) * 8);
        const unsigned short* pe = rowp + soff + loff;
#pragma unroll
        for (int tt = 0; tt < 8; ++tt) {
            const bf16x8 a = *reinterpret_cast<const bf16x8*>(pe + tt * 512);
            acc[tt][0] = __builtin_amdgcn_mfma_f32_16x16x32_bf16(a, b0, acc[tt][0], 0, 0, 0);
            acc[tt][1] = __builtin_amdgcn_mfma_f32_16x16x32_bf16(a, b1, acc[tt][1], 0, 0, 0);
        }
    }

    // D: out channel = lane&15 (+16 for acc1), pixel = xseg + tt*16 + (lane>>4)*4 + j
    const int prow = (lane >> 4) << 2;
    float* op0 = out + ((size_t)b * OO + (lane & 15)) * HW + (size_t)h * WW + xseg + prow;
#pragma unroll
    for (int tt = 0; tt < 8; ++tt) {
        *reinterpret_cast<f32x4*>(op0 + tt * 16) = acc[tt][0];
        *reinterpret_cast<f32x4*>(op0 + tt * 16 + (size_t)16 * HW) = acc[tt][1];
    }
}

// ---------------------------------------------------------------------------
extern "C" void kernel_launch(void* const* d_in, const int* in_sizes, int n_in,
                              void* d_out, int out_size, void* d_ws, size_t ws_size,
                              hipStream_t stream) {
    const float* x     = (const float*)d_in[0];
    const float* sigma = (const float*)d_in[1];
    const float* wgt   = (const float*)d_in[2];
    float* out = (float*)d_out;

    // ws layout: [ meta: 64 ints ][ wb2: 36*1024 bf16 ] (128 KB reserved)
    //            [ xbt: BB*HP*WP*CC bf16 padded image ]
    int* meta           = (int*)d_ws;
    unsigned short* wb2 = (unsigned short*)((char*)d_ws + 256);
    unsigned short* xbt = (unsigned short*)((char*)d_ws + 131072);

    wtrans_kernel<<<36, 256, 0, stream>>>(wgt, sigma, meta, wb2);
    blur_t_kernel<<<BB * 64, 256, 0, stream>>>(x, sigma, xbt);
    mix4_kernel<<<BB * 64, 512, 0, stream>>>(xbt, meta, wb2, out);
}